// Round 7
// baseline (273.083 us; speedup 1.0000x reference)
//
#include <hip/hip_runtime.h>
#include <stdint.h>

#define NN   50000
#define DIMK 512
#define HIDN 256
#define NE   800000

#define SCAN_ITEMS 4
#define SCAN_BLK 256
#define SCAN_PER_BLOCK (SCAN_ITEMS * SCAN_BLK)              // 1024
#define NBLK ((NN + SCAN_PER_BLOCK - 1) / SCAN_PER_BLOCK)   // 49

typedef float f32x4  __attribute__((ext_vector_type(4)));
typedef float f32x16 __attribute__((ext_vector_type(16)));
typedef short s16x8  __attribute__((ext_vector_type(8)));

static __device__ __forceinline__ unsigned short f2bf(float f) {
  union { float f; uint32_t u; } v; v.f = f;
  uint32_t u = v.u;
  u += 0x7fffu + ((u >> 16) & 1u);   // RNE
  return (unsigned short)(u >> 16);
}

static __device__ __forceinline__ uint32_t cvt_pk_bf16(float lo, float hi) {
  uint32_t r;
  asm("v_cvt_pk_bf16_f32 %0, %1, %2" : "=v"(r) : "v"(lo), "v"(hi));
  return r;   // low16 = bf16(lo), high16 = bf16(hi), RNE
}

// ---------------- degree histogram ----------------
__global__ void k_hist(const int* __restrict__ edst, int* __restrict__ cnt) {
  int e = blockIdx.x * 256 + threadIdx.x;
  if (e < NE) atomicAdd(&cnt[edst[e]], 1);
}

// ---------------- device-wide scan, stage 1: per-block sums ----------------
__global__ __launch_bounds__(256) void k_blocksum(const int* __restrict__ cnt,
                                                  int* __restrict__ blocksum) {
  const int t = threadIdx.x;
  const int base = blockIdx.x * SCAN_PER_BLOCK + t * SCAN_ITEMS;
  int s = 0;
#pragma unroll
  for (int j = 0; j < SCAN_ITEMS; ++j) { int i = base + j; if (i < NN) s += cnt[i]; }
#pragma unroll
  for (int o = 1; o < 64; o <<= 1) s += __shfl_xor(s, o);
  __shared__ int wsum[4];
  if ((t & 63) == 0) wsum[t >> 6] = s;
  __syncthreads();
  if (t == 0) blocksum[blockIdx.x] = wsum[0] + wsum[1] + wsum[2] + wsum[3];
}

// ---------------- stage 2: scan the 49 block sums (one wave) ----------------
__global__ void k_scanblocks(const int* __restrict__ blocksum, int* __restrict__ blockoff) {
  const int t = threadIdx.x;   // 64 threads
  int own = (t < NBLK) ? blocksum[t] : 0;
  int v = own;
#pragma unroll
  for (int o = 1; o < 64; o <<= 1) { int u = __shfl_up(v, o); if (t >= o) v += u; }
  if (t < NBLK) blockoff[t] = v - own;   // exclusive
}

// ---------------- stage 3: local scan + write offsets/cursor/dis ----------------
__global__ __launch_bounds__(256) void k_finalize(const int* __restrict__ cnt,
                                                  const int* __restrict__ blockoff,
                                                  int* __restrict__ offsets,
                                                  int* __restrict__ cursor,
                                                  float* __restrict__ dis) {
  const int t = threadIdx.x;
  const int l = t & 63, w = t >> 6;
  const int base = blockIdx.x * SCAN_PER_BLOCK + t * SCAN_ITEMS;
  int c[SCAN_ITEMS]; int s = 0;
#pragma unroll
  for (int j = 0; j < SCAN_ITEMS; ++j) { int i = base + j; c[j] = (i < NN) ? cnt[i] : 0; s += c[j]; }
  const int own = s;
#pragma unroll
  for (int o = 1; o < 64; o <<= 1) { int u = __shfl_up(s, o); if (l >= o) s += u; }
  __shared__ int wt[4];
  if (l == 63) wt[w] = s;
  __syncthreads();
  int waveoff = 0;
  for (int ww = 0; ww < w; ++ww) waveoff += wt[ww];
  int run = blockoff[blockIdx.x] + waveoff + (s - own);   // exclusive prefix
#pragma unroll
  for (int j = 0; j < SCAN_ITEMS; ++j) {
    int i = base + j;
    if (i < NN) {
      offsets[i] = run;
      cursor[i]  = run;
      dis[i] = rsqrtf((float)(c[j] + 1));   // +1 self loop
      run += c[j];
    }
  }
  if (blockIdx.x == 0 && t == 0) offsets[NN] = NE;
}

// ---------------- CSR scatter ----------------
__global__ void k_scatter(const int* __restrict__ esrc, const int* __restrict__ edst,
                          int* __restrict__ cursor, int* __restrict__ ssorted) {
  int e = blockIdx.x * 256 + threadIdx.x;
  if (e < NE) {
    int d = edst[e];
    int p = atomicAdd(&cursor[d], 1);
    ssorted[p] = esrc[e];
  }
}

// ---------------- W1^T -> bf16, fragment-contiguous image for 32x32x16 MFMA ----
// fragment (t, j): 1KB, lane l, elem i at byte (t*8+j)*1024 + l*16 + 2*i
// holds element k = t*16 + 8*(l>>5) + i, col = j*32 + (l&31)
__global__ void k_prep_w1t(const float* __restrict__ W1, char* __restrict__ w1t) {
  int tid = blockIdx.x * 256 + threadIdx.x;   // 512*256 = 131072 = DIMK*HIDN
  int c  = tid & 255;
  int k  = tid >> 8;
  int t  = k >> 4;
  int kk = k & 15;
  int g  = kk >> 3;
  int i  = kk & 7;
  int j  = c >> 5;
  int cc = c & 31;
  unsigned short v = f2bf(W1[k * HIDN + c]);
  *(unsigned short*)(w1t + (t * 8 + j) * 1024 + (g * 32 + cc) * 16 + i * 2) = v;
}

// ---------------- GEMM1: h1s = bf16(dis[row] * (x @ W1)) ----------------
// SINGLE-WAVE workgroup (64 threads): one wave owns a 32-row stripe x 128-col
// half. A staged coalesced into padded LDS [32][17] float4 (no XOR, no
// cross-wave races), transpose-read as fragments; B direct from the proven
// L2-resident w1t image with 1-step register prefetch.
__global__ __launch_bounds__(64, 3) void k_gemm1(const float* __restrict__ x,
                                                 const char* __restrict__ w1t,
                                                 const float* __restrict__ dis,
                                                 unsigned short* __restrict__ h1s) {
  __shared__ float4 lds4[32 * 17];     // padded: row stride 17 float4s (8704 B)
  const int l = threadIdx.x;           // 0..63
  const int wid = blockIdx.x;          // one wave per block
  const int stripe = wid >> 1;
  const int R0 = stripe * 32;
  const int j0 = (wid & 1) * 4;        // column half: fragments j0..j0+3
  const int h = l >> 5;

  // staging geometry: iter q covers rows q*4 + (l>>4), slot l&15
  const int st_r = l >> 4;             // 0..3
  const int st_s = l & 15;
  const float4* x4 = (const float4*)x;

  int gidx[8];
#pragma unroll
  for (int q = 0; q < 8; ++q) {
    int row = R0 + q * 4 + st_r;
    if (row >= NN) row = NN - 1;       // clamp; stores guarded later
    gidx[q] = row * (DIMK / 4) + st_s; // float4 index (add kt*16 per tile)
  }

  // compute geometry
  const int r_loc = l & 31;
  const char* wb = w1t + j0 * 1024 + l * 16;   // B base (col half)

  f32x16 acc[4];
#pragma unroll
  for (int j = 0; j < 4; ++j)
#pragma unroll
    for (int g = 0; g < 16; ++g) acc[j][g] = 0.f;

  // preload tile 0
  float4 G[8];
#pragma unroll
  for (int q = 0; q < 8; ++q) G[q] = x4[gidx[q]];

#pragma unroll
  for (int kt = 0; kt < 8; ++kt) {
    __syncthreads();                   // reads of previous tile done (1 wave: cheap)
#pragma unroll
    for (int q = 0; q < 8; ++q)
      lds4[(q * 4 + st_r) * 17 + st_s] = G[q];
    if (kt < 7) {
      const int b = (kt + 1) * 16;
#pragma unroll
      for (int q = 0; q < 8; ++q) G[q] = x4[gidx[q] + b];
    }
    __syncthreads();                   // staged writes visible

    // 4 k-steps of 16; B 1-step register prefetch (fully static rotation)
    s16x8 Bc[4], Bn[4];
#pragma unroll
    for (int j = 0; j < 4; ++j)
      Bc[j] = *(const s16x8*)(wb + (kt * 4 + 0) * 8192 + j * 1024);
#pragma unroll
    for (int ks = 0; ks < 4; ++ks) {
      if (ks < 3) {
#pragma unroll
        for (int j = 0; j < 4; ++j)
          Bn[j] = *(const s16x8*)(wb + (kt * 4 + ks + 1) * 8192 + j * 1024);
      }
      const int slo = ks * 4 + h * 2;  // float4 slot in row: k = slo*4..slo*4+7
      const float4 alo = lds4[r_loc * 17 + slo];
      const float4 ahi = lds4[r_loc * 17 + slo + 1];
      union { s16x8 v; uint32_t u[4]; } AF;
      AF.u[0] = cvt_pk_bf16(alo.x, alo.y);
      AF.u[1] = cvt_pk_bf16(alo.z, alo.w);
      AF.u[2] = cvt_pk_bf16(ahi.x, ahi.y);
      AF.u[3] = cvt_pk_bf16(ahi.z, ahi.w);
#pragma unroll
      for (int j = 0; j < 4; ++j)
        acc[j] = __builtin_amdgcn_mfma_f32_32x32x16_bf16(AF.v, Bc[j], acc[j], 0, 0, 0);
#pragma unroll
      for (int j = 0; j < 4; ++j) Bc[j] = Bn[j];
    }
  }

  // epilogue: D col = (j0+j)*32 + (l&31), row = (g&3) + 8*(g>>2) + 4*h
  const int cc = l & 31;
  float dv[16];
#pragma unroll
  for (int g = 0; g < 16; ++g) {
    int row = R0 + (g & 3) + 8 * (g >> 2) + 4 * h;
    dv[g] = (row < NN) ? dis[row] : 0.f;
  }
#pragma unroll
  for (int j = 0; j < 4; ++j) {
#pragma unroll
    for (int g = 0; g < 16; ++g) {
      int row = R0 + (g & 3) + 8 * (g >> 2) + 4 * h;
      if (row < NN)
        h1s[(size_t)row * HIDN + (j0 + j) * 32 + cc] = f2bf(acc[j][g] * dv[g]);
    }
  }
}

// ---------------- fused: aggregate h1s (CSR) + b1 + ReLU + @W2 -> h2s (pre-scaled) ----------------
__global__ __launch_bounds__(256) void k_agg1(const unsigned short* __restrict__ h1s,
                                              const int* __restrict__ offsets,
                                              const int* __restrict__ ssorted,
                                              const float* __restrict__ dis,
                                              const float* __restrict__ b1,
                                              const float* __restrict__ W2,
                                              float* __restrict__ h2s) {
  const int w = threadIdx.x >> 6;
  const int l = threadIdx.x & 63;
  const int d = blockIdx.x * 4 + w;
  if (d >= NN) return;

  float a0, a1, a2, a3;
  {                                    // self term
    uint2 v = *(const uint2*)(h1s + (size_t)d * HIDN + l * 4);
    a0 = __uint_as_float(v.x << 16);
    a1 = __uint_as_float(v.x & 0xffff0000u);
    a2 = __uint_as_float(v.y << 16);
    a3 = __uint_as_float(v.y & 0xffff0000u);
  }
  const int off0 = offsets[d], off1 = offsets[d + 1];
  int e = off0;
  for (; e + 4 <= off1; e += 4) {
    int s0 = ssorted[e], s1 = ssorted[e + 1], s2 = ssorted[e + 2], s3 = ssorted[e + 3];
    uint2 v0 = *(const uint2*)(h1s + (size_t)s0 * HIDN + l * 4);
    uint2 v1 = *(const uint2*)(h1s + (size_t)s1 * HIDN + l * 4);
    uint2 v2 = *(const uint2*)(h1s + (size_t)s2 * HIDN + l * 4);
    uint2 v3 = *(const uint2*)(h1s + (size_t)s3 * HIDN + l * 4);
    a0 += __uint_as_float(v0.x << 16) + __uint_as_float(v1.x << 16) +
          __uint_as_float(v2.x << 16) + __uint_as_float(v3.x << 16);
    a1 += __uint_as_float(v0.x & 0xffff0000u) + __uint_as_float(v1.x & 0xffff0000u) +
          __uint_as_float(v2.x & 0xffff0000u) + __uint_as_float(v3.x & 0xffff0000u);
    a2 += __uint_as_float(v0.y << 16) + __uint_as_float(v1.y << 16) +
          __uint_as_float(v2.y << 16) + __uint_as_float(v3.y << 16);
    a3 += __uint_as_float(v0.y & 0xffff0000u) + __uint_as_float(v1.y & 0xffff0000u) +
          __uint_as_float(v2.y & 0xffff0000u) + __uint_as_float(v3.y & 0xffff0000u);
  }
  for (; e < off1; ++e) {
    int s = ssorted[e];
    uint2 v = *(const uint2*)(h1s + (size_t)s * HIDN + l * 4);
    a0 += __uint_as_float(v.x << 16);
    a1 += __uint_as_float(v.x & 0xffff0000u);
    a2 += __uint_as_float(v.y << 16);
    a3 += __uint_as_float(v.y & 0xffff0000u);
  }

  const float dsd = dis[d];
  const int c0 = l * 4;
  float r0 = fmaxf(a0 * dsd + b1[c0 + 0], 0.f);
  float r1 = fmaxf(a1 * dsd + b1[c0 + 1], 0.f);
  float r2 = fmaxf(a2 * dsd + b1[c0 + 2], 0.f);
  float r3 = fmaxf(a3 * dsd + b1[c0 + 3], 0.f);

  float p0 = r0 * W2[(c0 + 0) * 2] + r1 * W2[(c0 + 1) * 2] +
             r2 * W2[(c0 + 2) * 2] + r3 * W2[(c0 + 3) * 2];
  float p1 = r0 * W2[(c0 + 0) * 2 + 1] + r1 * W2[(c0 + 1) * 2 + 1] +
             r2 * W2[(c0 + 2) * 2 + 1] + r3 * W2[(c0 + 3) * 2 + 1];
#pragma unroll
  for (int o = 1; o < 64; o <<= 1) {
    p0 += __shfl_xor(p0, o);
    p1 += __shfl_xor(p1, o);
  }
  if (l == 0) {
    h2s[(size_t)d * 2 + 0] = dsd * p0;   // pre-scaled by dis[d] for layer-2 gather
    h2s[(size_t)d * 2 + 1] = dsd * p1;
  }
}

// ---------------- layer-2 aggregation (2 cols) ----------------
__global__ void k_agg2(const float* __restrict__ h2s, const int* __restrict__ offsets,
                       const int* __restrict__ ssorted, const float* __restrict__ dis,
                       const float* __restrict__ b2, float* __restrict__ out) {
  int d = blockIdx.x * 256 + threadIdx.x;
  if (d >= NN) return;
  float2 sv = *(const float2*)(h2s + (size_t)d * 2);
  float a0 = sv.x, a1 = sv.y;
  int off0 = offsets[d], off1 = offsets[d + 1];
  int e = off0;
  for (; e + 4 <= off1; e += 4) {
    int s0 = ssorted[e], s1 = ssorted[e + 1], s2 = ssorted[e + 2], s3 = ssorted[e + 3];
    float2 v0 = *(const float2*)(h2s + (size_t)s0 * 2);
    float2 v1 = *(const float2*)(h2s + (size_t)s1 * 2);
    float2 v2 = *(const float2*)(h2s + (size_t)s2 * 2);
    float2 v3 = *(const float2*)(h2s + (size_t)s3 * 2);
    a0 += v0.x + v1.x + v2.x + v3.x;
    a1 += v0.y + v1.y + v2.y + v3.y;
  }
  for (; e < off1; ++e) {
    int s = ssorted[e];
    float2 v = *(const float2*)(h2s + (size_t)s * 2);
    a0 += v.x; a1 += v.y;
  }
  float dsd = dis[d];
  out[(size_t)d * 2 + 0] = dsd * a0 + b2[0];
  out[(size_t)d * 2 + 1] = dsd * a1 + b2[1];
}

extern "C" void kernel_launch(void* const* d_in, const int* in_sizes, int n_in,
                              void* d_out, int out_size, void* d_ws, size_t ws_size,
                              hipStream_t stream) {
  (void)in_sizes; (void)n_in; (void)out_size; (void)ws_size;
  const float* x   = (const float*)d_in[0];
  const float* W1  = (const float*)d_in[1];
  const float* b1  = (const float*)d_in[2];
  const float* W2  = (const float*)d_in[3];
  const float* b2  = (const float*)d_in[4];
  const int*   ei  = (const int*)d_in[5];
  const int* esrc = ei;
  const int* edst = ei + NE;
  float* out = (float*)d_out;

  char* ws = (char*)d_ws;
  // workspace layout (all 16B-aligned), total ~30.3 MB
  unsigned short* h1s = (unsigned short*)(ws + 0);          // 25,600,000 B
  char*  w1t     = ws + 25600000;                           //    262,144 B
  float* dis     = (float*)(ws + 25862144);                 //    200,000 B
  float* h2s     = (float*)(ws + 26062144);                 //    400,000 B
  int*   cnt     = (int*)(ws + 26462144);                   //    200,000 B
  int*   offsets = (int*)(ws + 26662144);                   //    200,004 B
  int*   cursor  = (int*)(ws + 26862208);                   //    200,000 B
  int*   ssorted = (int*)(ws + 27062208);                   //  3,200,000 B
  int*   blocksum= (int*)(ws + 30262208);                   //        196 B
  int*   blockoff= (int*)(ws + 30262464);                   //        196 B

  hipMemsetAsync(cnt, 0, NN * sizeof(int), stream);
  k_hist<<<(NE + 255) / 256, 256, 0, stream>>>(edst, cnt);
  k_blocksum<<<NBLK, 256, 0, stream>>>(cnt, blocksum);
  k_scanblocks<<<1, 64, 0, stream>>>(blocksum, blockoff);
  k_finalize<<<NBLK, 256, 0, stream>>>(cnt, blockoff, offsets, cursor, dis);
  k_scatter<<<(NE + 255) / 256, 256, 0, stream>>>(esrc, edst, cursor, ssorted);
  k_prep_w1t<<<(DIMK * HIDN) / 256, 256, 0, stream>>>(W1, w1t);
  {
    const int nwaves = 2 * ((NN + 31) / 32);        // 3126 single-wave blocks
    k_gemm1<<<nwaves, 64, 0, stream>>>(x, w1t, dis, h1s);
  }
  k_agg1<<<(NN + 3) / 4, 256, 0, stream>>>(h1s, offsets, ssorted, dis, b1, W2, h2s);
  k_agg2<<<(NN + 255) / 256, 256, 0, stream>>>(h2s, offsets, ssorted, dis, b2, out);
}

// Round 8
// 215.842 us; speedup vs baseline: 1.2652x; 1.2652x over previous
//
#include <hip/hip_runtime.h>
#include <stdint.h>

#define NN   50000
#define DIMK 512
#define HIDN 256
#define NE   800000

#define SCAN_ITEMS 4
#define SCAN_BLK 256
#define SCAN_PER_BLOCK (SCAN_ITEMS * SCAN_BLK)              // 1024
#define NBLK ((NN + SCAN_PER_BLOCK - 1) / SCAN_PER_BLOCK)   // 49

typedef float f32x4  __attribute__((ext_vector_type(4)));
typedef float f32x16 __attribute__((ext_vector_type(16)));
typedef short s16x8  __attribute__((ext_vector_type(8)));

static __device__ __forceinline__ unsigned short f2bf(float f) {
  union { float f; uint32_t u; } v; v.f = f;
  uint32_t u = v.u;
  u += 0x7fffu + ((u >> 16) & 1u);   // RNE
  return (unsigned short)(u >> 16);
}

static __device__ __forceinline__ uint32_t cvt_pk_bf16(float lo, float hi) {
  uint32_t r;
  asm("v_cvt_pk_bf16_f32 %0, %1, %2" : "=v"(r) : "v"(lo), "v"(hi));
  return r;   // low16 = bf16(lo), high16 = bf16(hi), RNE
}

// ---------------- degree histogram ----------------
__global__ void k_hist(const int* __restrict__ edst, int* __restrict__ cnt) {
  int e = blockIdx.x * 256 + threadIdx.x;
  if (e < NE) atomicAdd(&cnt[edst[e]], 1);
}

// ---------------- device-wide scan, stage 1: per-block sums ----------------
__global__ __launch_bounds__(256) void k_blocksum(const int* __restrict__ cnt,
                                                  int* __restrict__ blocksum) {
  const int t = threadIdx.x;
  const int base = blockIdx.x * SCAN_PER_BLOCK + t * SCAN_ITEMS;
  int s = 0;
#pragma unroll
  for (int j = 0; j < SCAN_ITEMS; ++j) { int i = base + j; if (i < NN) s += cnt[i]; }
#pragma unroll
  for (int o = 1; o < 64; o <<= 1) s += __shfl_xor(s, o);
  __shared__ int wsum[4];
  if ((t & 63) == 0) wsum[t >> 6] = s;
  __syncthreads();
  if (t == 0) blocksum[blockIdx.x] = wsum[0] + wsum[1] + wsum[2] + wsum[3];
}

// ---------------- stage 2: scan the 49 block sums (one wave) ----------------
__global__ void k_scanblocks(const int* __restrict__ blocksum, int* __restrict__ blockoff) {
  const int t = threadIdx.x;   // 64 threads
  int own = (t < NBLK) ? blocksum[t] : 0;
  int v = own;
#pragma unroll
  for (int o = 1; o < 64; o <<= 1) { int u = __shfl_up(v, o); if (t >= o) v += u; }
  if (t < NBLK) blockoff[t] = v - own;   // exclusive
}

// ---------------- stage 3: local scan + write offsets/cursor/dis ----------------
__global__ __launch_bounds__(256) void k_finalize(const int* __restrict__ cnt,
                                                  const int* __restrict__ blockoff,
                                                  int* __restrict__ offsets,
                                                  int* __restrict__ cursor,
                                                  float* __restrict__ dis) {
  const int t = threadIdx.x;
  const int l = t & 63, w = t >> 6;
  const int base = blockIdx.x * SCAN_PER_BLOCK + t * SCAN_ITEMS;
  int c[SCAN_ITEMS]; int s = 0;
#pragma unroll
  for (int j = 0; j < SCAN_ITEMS; ++j) { int i = base + j; c[j] = (i < NN) ? cnt[i] : 0; s += c[j]; }
  const int own = s;
#pragma unroll
  for (int o = 1; o < 64; o <<= 1) { int u = __shfl_up(s, o); if (l >= o) s += u; }
  __shared__ int wt[4];
  if (l == 63) wt[w] = s;
  __syncthreads();
  int waveoff = 0;
  for (int ww = 0; ww < w; ++ww) waveoff += wt[ww];
  int run = blockoff[blockIdx.x] + waveoff + (s - own);   // exclusive prefix
#pragma unroll
  for (int j = 0; j < SCAN_ITEMS; ++j) {
    int i = base + j;
    if (i < NN) {
      offsets[i] = run;
      cursor[i]  = run;
      dis[i] = rsqrtf((float)(c[j] + 1));   // +1 self loop
      run += c[j];
    }
  }
  if (blockIdx.x == 0 && t == 0) offsets[NN] = NE;
}

// ---------------- CSR scatter ----------------
__global__ void k_scatter(const int* __restrict__ esrc, const int* __restrict__ edst,
                          int* __restrict__ cursor, int* __restrict__ ssorted) {
  int e = blockIdx.x * 256 + threadIdx.x;
  if (e < NE) {
    int d = edst[e];
    int p = atomicAdd(&cursor[d], 1);
    ssorted[p] = esrc[e];
  }
}

// ---------------- W1^T -> bf16, fragment-contiguous image for 32x32x16 MFMA ----
// fragment (t, j): 1KB, lane l, elem i at byte (t*8+j)*1024 + l*16 + 2*i
// holds element k = t*16 + 8*(l>>5) + i, col = j*32 + (l&31)
__global__ void k_prep_w1t(const float* __restrict__ W1, char* __restrict__ w1t) {
  int tid = blockIdx.x * 256 + threadIdx.x;   // 512*256 = 131072 = DIMK*HIDN
  int c  = tid & 255;
  int k  = tid >> 8;
  int t  = k >> 4;
  int kk = k & 15;
  int g  = kk >> 3;
  int i  = kk & 7;
  int j  = c >> 5;
  int cc = c & 31;
  unsigned short v = f2bf(W1[k * HIDN + c]);
  *(unsigned short*)(w1t + (t * 8 + j) * 1024 + (g * 32 + cc) * 16 + i * 2) = v;
}

// ---------------- GEMM1 (R4-proven): h1s = bf16(dis[row] * (x @ W1)) --------
// One independent wave per (32-row stripe, 128-col half). No LDS, no barriers.
// mfma_f32_32x32x16_bf16; A prefetch 4 deep, B prefetch 2 deep; acc = 64 AGPR.
#define GSTEP(T, AC, BC)                                                        \
  {                                                                             \
    union { s16x8 v; uint32_t u[4]; } AF;                                       \
    AF.u[0] = cvt_pk_bf16(AC[0].x, AC[0].y);                                    \
    AF.u[1] = cvt_pk_bf16(AC[0].z, AC[0].w);                                    \
    AF.u[2] = cvt_pk_bf16(AC[1].x, AC[1].y);                                    \
    AF.u[3] = cvt_pk_bf16(AC[1].z, AC[1].w);                                    \
    _Pragma("unroll")                                                           \
    for (int j = 0; j < 4; ++j)                                                 \
      acc[j] = __builtin_amdgcn_mfma_f32_32x32x16_bf16(AF.v, BC[j], acc[j], 0, 0, 0); \
    if ((T) + 2 < 32) {                                                         \
      _Pragma("unroll")                                                         \
      for (int j = 0; j < 4; ++j)                                               \
        BC[j] = *(const s16x8*)(wb + ((T) + 2) * 8192 + j * 1024);              \
    }                                                                           \
    if ((T) + 4 < 32) {                                                         \
      AC[0] = ap[((T) + 4) * 4];                                                \
      AC[1] = ap[((T) + 4) * 4 + 1];                                            \
    }                                                                           \
  }

__global__ __launch_bounds__(256, 3) void k_gemm1(const float* __restrict__ x,
                                                  const char* __restrict__ w1t,
                                                  const float* __restrict__ dis,
                                                  unsigned short* __restrict__ h1s) {
  const int l = threadIdx.x & 63;
  const int wid = (blockIdx.x * 256 + threadIdx.x) >> 6;
  const int stripe = wid >> 1;
  const int R0 = stripe * 32;
  if (R0 >= NN) return;
  const int j0 = (wid & 1) * 4;       // column half: fragments j0..j0+3
  const int h = l >> 5;
  int ra = R0 + (l & 31);
  if (ra >= NN) ra = NN - 1;

  const float4* ap = (const float4*)(x + (size_t)ra * DIMK) + h * 2;
  const char* wb = w1t + j0 * 1024 + l * 16;

  f32x16 acc[4];
#pragma unroll
  for (int j = 0; j < 4; ++j)
#pragma unroll
    for (int g = 0; g < 16; ++g) acc[j][g] = 0.f;

  // prologue: A steps 0..3, B steps 0..1
  float4 A0[2], A1[2], A2[2], A3[2];
  A0[0] = ap[0];  A0[1] = ap[1];
  A1[0] = ap[4];  A1[1] = ap[5];
  A2[0] = ap[8];  A2[1] = ap[9];
  A3[0] = ap[12]; A3[1] = ap[13];
  s16x8 Ba[4], Bb[4];
#pragma unroll
  for (int j = 0; j < 4; ++j) Ba[j] = *(const s16x8*)(wb + j * 1024);
#pragma unroll
  for (int j = 0; j < 4; ++j) Bb[j] = *(const s16x8*)(wb + 8192 + j * 1024);

#pragma unroll
  for (int q = 0; q < 8; ++q) {
    GSTEP(4 * q + 0, A0, Ba);
    GSTEP(4 * q + 1, A1, Bb);
    GSTEP(4 * q + 2, A2, Ba);
    GSTEP(4 * q + 3, A3, Bb);
  }

  // epilogue: D col = (j0+j)*32 + (l&31), row = (g&3) + 8*(g>>2) + 4*(l>>5)
  const int cc = l & 31;
  float dv[16];
#pragma unroll
  for (int g = 0; g < 16; ++g) {
    int row = R0 + (g & 3) + 8 * (g >> 2) + 4 * h;
    dv[g] = (row < NN) ? dis[row] : 0.f;
  }
#pragma unroll
  for (int j = 0; j < 4; ++j) {
#pragma unroll
    for (int g = 0; g < 16; ++g) {
      int row = R0 + (g & 3) + 8 * (g >> 2) + 4 * h;
      if (row < NN)
        h1s[(size_t)row * HIDN + (j0 + j) * 32 + cc] = f2bf(acc[j][g] * dv[g]);
    }
  }
}

// ---------------- fused: aggregate h1s (CSR) + b1 + ReLU + @W2 -> h2s (pre-scaled) ----------------
#define ACC_EDGE(VV)                                                            \
  a0 += __uint_as_float((VV).x << 16);                                          \
  a1 += __uint_as_float((VV).x & 0xffff0000u);                                  \
  a2 += __uint_as_float((VV).y << 16);                                          \
  a3 += __uint_as_float((VV).y & 0xffff0000u);

__global__ __launch_bounds__(256) void k_agg1(const unsigned short* __restrict__ h1s,
                                              const int* __restrict__ offsets,
                                              const int* __restrict__ ssorted,
                                              const float* __restrict__ dis,
                                              const float* __restrict__ b1,
                                              const float* __restrict__ W2,
                                              float* __restrict__ h2s) {
  const int w = threadIdx.x >> 6;
  const int l = threadIdx.x & 63;
  const int d = blockIdx.x * 4 + w;
  if (d >= NN) return;

  float a0, a1, a2, a3;
  {                                    // self term
    uint2 v = *(const uint2*)(h1s + (size_t)d * HIDN + l * 4);
    a0 = __uint_as_float(v.x << 16);
    a1 = __uint_as_float(v.x & 0xffff0000u);
    a2 = __uint_as_float(v.y << 16);
    a3 = __uint_as_float(v.y & 0xffff0000u);
  }
  const int off0 = offsets[d], off1 = offsets[d + 1];
  int e = off0;
  for (; e + 8 <= off1; e += 8) {      // 8-deep MLP: 8 outstanding row-gathers
    int s0 = ssorted[e],     s1 = ssorted[e + 1], s2 = ssorted[e + 2], s3 = ssorted[e + 3];
    int s4 = ssorted[e + 4], s5 = ssorted[e + 5], s6 = ssorted[e + 6], s7 = ssorted[e + 7];
    uint2 v0 = *(const uint2*)(h1s + (size_t)s0 * HIDN + l * 4);
    uint2 v1 = *(const uint2*)(h1s + (size_t)s1 * HIDN + l * 4);
    uint2 v2 = *(const uint2*)(h1s + (size_t)s2 * HIDN + l * 4);
    uint2 v3 = *(const uint2*)(h1s + (size_t)s3 * HIDN + l * 4);
    uint2 v4 = *(const uint2*)(h1s + (size_t)s4 * HIDN + l * 4);
    uint2 v5 = *(const uint2*)(h1s + (size_t)s5 * HIDN + l * 4);
    uint2 v6 = *(const uint2*)(h1s + (size_t)s6 * HIDN + l * 4);
    uint2 v7 = *(const uint2*)(h1s + (size_t)s7 * HIDN + l * 4);
    ACC_EDGE(v0) ACC_EDGE(v1) ACC_EDGE(v2) ACC_EDGE(v3)
    ACC_EDGE(v4) ACC_EDGE(v5) ACC_EDGE(v6) ACC_EDGE(v7)
  }
  for (; e + 4 <= off1; e += 4) {
    int s0 = ssorted[e], s1 = ssorted[e + 1], s2 = ssorted[e + 2], s3 = ssorted[e + 3];
    uint2 v0 = *(const uint2*)(h1s + (size_t)s0 * HIDN + l * 4);
    uint2 v1 = *(const uint2*)(h1s + (size_t)s1 * HIDN + l * 4);
    uint2 v2 = *(const uint2*)(h1s + (size_t)s2 * HIDN + l * 4);
    uint2 v3 = *(const uint2*)(h1s + (size_t)s3 * HIDN + l * 4);
    ACC_EDGE(v0) ACC_EDGE(v1) ACC_EDGE(v2) ACC_EDGE(v3)
  }
  for (; e < off1; ++e) {
    int s = ssorted[e];
    uint2 v = *(const uint2*)(h1s + (size_t)s * HIDN + l * 4);
    ACC_EDGE(v)
  }

  const float dsd = dis[d];
  const int c0 = l * 4;
  float r0 = fmaxf(a0 * dsd + b1[c0 + 0], 0.f);
  float r1 = fmaxf(a1 * dsd + b1[c0 + 1], 0.f);
  float r2 = fmaxf(a2 * dsd + b1[c0 + 2], 0.f);
  float r3 = fmaxf(a3 * dsd + b1[c0 + 3], 0.f);

  float p0 = r0 * W2[(c0 + 0) * 2] + r1 * W2[(c0 + 1) * 2] +
             r2 * W2[(c0 + 2) * 2] + r3 * W2[(c0 + 3) * 2];
  float p1 = r0 * W2[(c0 + 0) * 2 + 1] + r1 * W2[(c0 + 1) * 2 + 1] +
             r2 * W2[(c0 + 2) * 2 + 1] + r3 * W2[(c0 + 3) * 2 + 1];
#pragma unroll
  for (int o = 1; o < 64; o <<= 1) {
    p0 += __shfl_xor(p0, o);
    p1 += __shfl_xor(p1, o);
  }
  if (l == 0) {
    h2s[(size_t)d * 2 + 0] = dsd * p0;   // pre-scaled by dis[d] for layer-2 gather
    h2s[(size_t)d * 2 + 1] = dsd * p1;
  }
}

// ---------------- layer-2 aggregation (2 cols) ----------------
__global__ void k_agg2(const float* __restrict__ h2s, const int* __restrict__ offsets,
                       const int* __restrict__ ssorted, const float* __restrict__ dis,
                       const float* __restrict__ b2, float* __restrict__ out) {
  int d = blockIdx.x * 256 + threadIdx.x;
  if (d >= NN) return;
  float2 sv = *(const float2*)(h2s + (size_t)d * 2);
  float a0 = sv.x, a1 = sv.y;
  int off0 = offsets[d], off1 = offsets[d + 1];
  int e = off0;
  for (; e + 4 <= off1; e += 4) {
    int s0 = ssorted[e], s1 = ssorted[e + 1], s2 = ssorted[e + 2], s3 = ssorted[e + 3];
    float2 v0 = *(const float2*)(h2s + (size_t)s0 * 2);
    float2 v1 = *(const float2*)(h2s + (size_t)s1 * 2);
    float2 v2 = *(const float2*)(h2s + (size_t)s2 * 2);
    float2 v3 = *(const float2*)(h2s + (size_t)s3 * 2);
    a0 += v0.x + v1.x + v2.x + v3.x;
    a1 += v0.y + v1.y + v2.y + v3.y;
  }
  for (; e < off1; ++e) {
    int s = ssorted[e];
    float2 v = *(const float2*)(h2s + (size_t)s * 2);
    a0 += v.x; a1 += v.y;
  }
  float dsd = dis[d];
  out[(size_t)d * 2 + 0] = dsd * a0 + b2[0];
  out[(size_t)d * 2 + 1] = dsd * a1 + b2[1];
}

extern "C" void kernel_launch(void* const* d_in, const int* in_sizes, int n_in,
                              void* d_out, int out_size, void* d_ws, size_t ws_size,
                              hipStream_t stream) {
  (void)in_sizes; (void)n_in; (void)out_size; (void)ws_size;
  const float* x   = (const float*)d_in[0];
  const float* W1  = (const float*)d_in[1];
  const float* b1  = (const float*)d_in[2];
  const float* W2  = (const float*)d_in[3];
  const float* b2  = (const float*)d_in[4];
  const int*   ei  = (const int*)d_in[5];
  const int* esrc = ei;
  const int* edst = ei + NE;
  float* out = (float*)d_out;

  char* ws = (char*)d_ws;
  // workspace layout (all 16B-aligned), total ~30.3 MB
  unsigned short* h1s = (unsigned short*)(ws + 0);          // 25,600,000 B
  char*  w1t     = ws + 25600000;                           //    262,144 B
  float* dis     = (float*)(ws + 25862144);                 //    200,000 B
  float* h2s     = (float*)(ws + 26062144);                 //    400,000 B
  int*   cnt     = (int*)(ws + 26462144);                   //    200,000 B
  int*   offsets = (int*)(ws + 26662144);                   //    200,004 B
  int*   cursor  = (int*)(ws + 26862208);                   //    200,000 B
  int*   ssorted = (int*)(ws + 27062208);                   //  3,200,000 B
  int*   blocksum= (int*)(ws + 30262208);                   //        196 B
  int*   blockoff= (int*)(ws + 30262464);                   //        196 B

  hipMemsetAsync(cnt, 0, NN * sizeof(int), stream);
  k_hist<<<(NE + 255) / 256, 256, 0, stream>>>(edst, cnt);
  k_blocksum<<<NBLK, 256, 0, stream>>>(cnt, blocksum);
  k_scanblocks<<<1, 64, 0, stream>>>(blocksum, blockoff);
  k_finalize<<<NBLK, 256, 0, stream>>>(cnt, blockoff, offsets, cursor, dis);
  k_scatter<<<(NE + 255) / 256, 256, 0, stream>>>(esrc, edst, cursor, ssorted);
  k_prep_w1t<<<(DIMK * HIDN) / 256, 256, 0, stream>>>(W1, w1t);
  {
    const int nwaves = 2 * ((NN + 31) / 32);        // 3126
    const int nblk   = (nwaves + 3) / 4;            // 782
    k_gemm1<<<nblk, 256, 0, stream>>>(x, w1t, dis, h1s);
  }
  k_agg1<<<(NN + 3) / 4, 256, 0, stream>>>(h1s, offsets, ssorted, dis, b1, W2, h2s);
  k_agg2<<<(NN + 255) / 256, 256, 0, stream>>>(h2s, offsets, ssorted, dis, b2, out);
}

// Round 9
// 212.547 us; speedup vs baseline: 1.2848x; 1.0155x over previous
//
#include <hip/hip_runtime.h>
#include <stdint.h>

#define NN   50000
#define DIMK 512
#define HIDN 256
#define NE   800000

#define SCAN_ITEMS 4
#define SCAN_BLK 256
#define SCAN_PER_BLOCK (SCAN_ITEMS * SCAN_BLK)              // 1024
#define NBLK ((NN + SCAN_PER_BLOCK - 1) / SCAN_PER_BLOCK)   // 49

typedef float f32x4  __attribute__((ext_vector_type(4)));
typedef float f32x16 __attribute__((ext_vector_type(16)));
typedef short s16x8  __attribute__((ext_vector_type(8)));

static __device__ __forceinline__ unsigned short f2bf(float f) {
  union { float f; uint32_t u; } v; v.f = f;
  uint32_t u = v.u;
  u += 0x7fffu + ((u >> 16) & 1u);   // RNE
  return (unsigned short)(u >> 16);
}

static __device__ __forceinline__ uint32_t cvt_pk_bf16(float lo, float hi) {
  uint32_t r;
  asm("v_cvt_pk_bf16_f32 %0, %1, %2" : "=v"(r) : "v"(lo), "v"(hi));
  return r;   // low16 = bf16(lo), high16 = bf16(hi), RNE
}

// ---------------- degree histogram ----------------
__global__ void k_hist(const int* __restrict__ edst, int* __restrict__ cnt) {
  int e = blockIdx.x * 256 + threadIdx.x;
  if (e < NE) atomicAdd(&cnt[edst[e]], 1);
}

// ---------------- device-wide scan, stage 1: per-block sums ----------------
__global__ __launch_bounds__(256) void k_blocksum(const int* __restrict__ cnt,
                                                  int* __restrict__ blocksum) {
  const int t = threadIdx.x;
  const int base = blockIdx.x * SCAN_PER_BLOCK + t * SCAN_ITEMS;
  int s = 0;
#pragma unroll
  for (int j = 0; j < SCAN_ITEMS; ++j) { int i = base + j; if (i < NN) s += cnt[i]; }
#pragma unroll
  for (int o = 1; o < 64; o <<= 1) s += __shfl_xor(s, o);
  __shared__ int wsum[4];
  if ((t & 63) == 0) wsum[t >> 6] = s;
  __syncthreads();
  if (t == 0) blocksum[blockIdx.x] = wsum[0] + wsum[1] + wsum[2] + wsum[3];
}

// ---------------- stage 2: scan the 49 block sums (one wave) ----------------
__global__ void k_scanblocks(const int* __restrict__ blocksum, int* __restrict__ blockoff) {
  const int t = threadIdx.x;   // 64 threads
  int own = (t < NBLK) ? blocksum[t] : 0;
  int v = own;
#pragma unroll
  for (int o = 1; o < 64; o <<= 1) { int u = __shfl_up(v, o); if (t >= o) v += u; }
  if (t < NBLK) blockoff[t] = v - own;   // exclusive
}

// ---------------- stage 3: local scan + write offsets/cursor/dis ----------------
__global__ __launch_bounds__(256) void k_finalize(const int* __restrict__ cnt,
                                                  const int* __restrict__ blockoff,
                                                  int* __restrict__ offsets,
                                                  int* __restrict__ cursor,
                                                  float* __restrict__ dis) {
  const int t = threadIdx.x;
  const int l = t & 63, w = t >> 6;
  const int base = blockIdx.x * SCAN_PER_BLOCK + t * SCAN_ITEMS;
  int c[SCAN_ITEMS]; int s = 0;
#pragma unroll
  for (int j = 0; j < SCAN_ITEMS; ++j) { int i = base + j; c[j] = (i < NN) ? cnt[i] : 0; s += c[j]; }
  const int own = s;
#pragma unroll
  for (int o = 1; o < 64; o <<= 1) { int u = __shfl_up(s, o); if (l >= o) s += u; }
  __shared__ int wt[4];
  if (l == 63) wt[w] = s;
  __syncthreads();
  int waveoff = 0;
  for (int ww = 0; ww < w; ++ww) waveoff += wt[ww];
  int run = blockoff[blockIdx.x] + waveoff + (s - own);   // exclusive prefix
#pragma unroll
  for (int j = 0; j < SCAN_ITEMS; ++j) {
    int i = base + j;
    if (i < NN) {
      offsets[i] = run;
      cursor[i]  = run;
      dis[i] = rsqrtf((float)(c[j] + 1));   // +1 self loop
      run += c[j];
    }
  }
  if (blockIdx.x == 0 && t == 0) offsets[NN] = NE;
}

// ---------------- CSR scatter ----------------
__global__ void k_scatter(const int* __restrict__ esrc, const int* __restrict__ edst,
                          int* __restrict__ cursor, int* __restrict__ ssorted) {
  int e = blockIdx.x * 256 + threadIdx.x;
  if (e < NE) {
    int d = edst[e];
    int p = atomicAdd(&cursor[d], 1);
    ssorted[p] = esrc[e];
  }
}

// ---------------- W1^T -> bf16, fragment-contiguous image for 32x32x16 MFMA ----
// fragment (t, j): 1KB, lane l, elem i at byte (t*8+j)*1024 + l*16 + 2*i
// holds element k = t*16 + 8*(l>>5) + i, col = j*32 + (l&31)
__global__ void k_prep_w1t(const float* __restrict__ W1, char* __restrict__ w1t) {
  int tid = blockIdx.x * 256 + threadIdx.x;   // 512*256 = 131072 = DIMK*HIDN
  int c  = tid & 255;
  int k  = tid >> 8;
  int t  = k >> 4;
  int kk = k & 15;
  int g  = kk >> 3;
  int i  = kk & 7;
  int j  = c >> 5;
  int cc = c & 31;
  unsigned short v = f2bf(W1[k * HIDN + c]);
  *(unsigned short*)(w1t + (t * 8 + j) * 1024 + (g * 32 + cc) * 16 + i * 2) = v;
}

// ---------------- GEMM1 (R4 datapath, 1-wave blocks): h1s = bf16(dis*(x@W1)) --
// One independent wave per (32-row stripe, 128-col half). No LDS, no barriers.
// 1-wave blocks pack ~16/CU -> whole grid resident (~4 waves/SIMD) so the
// 4-deep A (L3 ~400cy) and 2-deep B (L2 ~200cy) prefetch is latency-covered.
#define GSTEP(T, AC, BC)                                                        \
  {                                                                             \
    union { s16x8 v; uint32_t u[4]; } AF;                                       \
    AF.u[0] = cvt_pk_bf16(AC[0].x, AC[0].y);                                    \
    AF.u[1] = cvt_pk_bf16(AC[0].z, AC[0].w);                                    \
    AF.u[2] = cvt_pk_bf16(AC[1].x, AC[1].y);                                    \
    AF.u[3] = cvt_pk_bf16(AC[1].z, AC[1].w);                                    \
    _Pragma("unroll")                                                           \
    for (int j = 0; j < 4; ++j)                                                 \
      acc[j] = __builtin_amdgcn_mfma_f32_32x32x16_bf16(AF.v, BC[j], acc[j], 0, 0, 0); \
    if ((T) + 2 < 32) {                                                         \
      _Pragma("unroll")                                                         \
      for (int j = 0; j < 4; ++j)                                               \
        BC[j] = *(const s16x8*)(wb + ((T) + 2) * 8192 + j * 1024);              \
    }                                                                           \
    if ((T) + 4 < 32) {                                                         \
      AC[0] = ap[((T) + 4) * 4];                                                \
      AC[1] = ap[((T) + 4) * 4 + 1];                                            \
    }                                                                           \
  }

__global__ __launch_bounds__(64, 4) void k_gemm1(const float* __restrict__ x,
                                                 const char* __restrict__ w1t,
                                                 const float* __restrict__ dis,
                                                 unsigned short* __restrict__ h1s) {
  const int l = threadIdx.x;           // 0..63, one wave per block
  const int wid = blockIdx.x;
  const int stripe = wid >> 1;
  const int R0 = stripe * 32;
  if (R0 >= NN) return;
  const int j0 = (wid & 1) * 4;       // column half: fragments j0..j0+3
  const int h = l >> 5;
  int ra = R0 + (l & 31);
  if (ra >= NN) ra = NN - 1;

  const float4* ap = (const float4*)(x + (size_t)ra * DIMK) + h * 2;
  const char* wb = w1t + j0 * 1024 + l * 16;

  f32x16 acc[4];
#pragma unroll
  for (int j = 0; j < 4; ++j)
#pragma unroll
    for (int g = 0; g < 16; ++g) acc[j][g] = 0.f;

  // prologue: A steps 0..3, B steps 0..1
  float4 A0[2], A1[2], A2[2], A3[2];
  A0[0] = ap[0];  A0[1] = ap[1];
  A1[0] = ap[4];  A1[1] = ap[5];
  A2[0] = ap[8];  A2[1] = ap[9];
  A3[0] = ap[12]; A3[1] = ap[13];
  s16x8 Ba[4], Bb[4];
#pragma unroll
  for (int j = 0; j < 4; ++j) Ba[j] = *(const s16x8*)(wb + j * 1024);
#pragma unroll
  for (int j = 0; j < 4; ++j) Bb[j] = *(const s16x8*)(wb + 8192 + j * 1024);

#pragma unroll
  for (int q = 0; q < 8; ++q) {
    GSTEP(4 * q + 0, A0, Ba);
    GSTEP(4 * q + 1, A1, Bb);
    GSTEP(4 * q + 2, A2, Ba);
    GSTEP(4 * q + 3, A3, Bb);
  }

  // epilogue: D col = (j0+j)*32 + (l&31), row = (g&3) + 8*(g>>2) + 4*(l>>5)
  const int cc = l & 31;
  float dv[16];
#pragma unroll
  for (int g = 0; g < 16; ++g) {
    int row = R0 + (g & 3) + 8 * (g >> 2) + 4 * h;
    dv[g] = (row < NN) ? dis[row] : 0.f;
  }
#pragma unroll
  for (int j = 0; j < 4; ++j) {
#pragma unroll
    for (int g = 0; g < 16; ++g) {
      int row = R0 + (g & 3) + 8 * (g >> 2) + 4 * h;
      if (row < NN)
        h1s[(size_t)row * HIDN + (j0 + j) * 32 + cc] = f2bf(acc[j][g] * dv[g]);
    }
  }
}

// ---------------- fused: aggregate h1s (CSR) + b1 + ReLU + @W2 -> h2s (pre-scaled) ----------------
#define ACC_EDGE(VV)                                                            \
  a0 += __uint_as_float((VV).x << 16);                                          \
  a1 += __uint_as_float((VV).x & 0xffff0000u);                                  \
  a2 += __uint_as_float((VV).y << 16);                                          \
  a3 += __uint_as_float((VV).y & 0xffff0000u);

__global__ __launch_bounds__(256) void k_agg1(const unsigned short* __restrict__ h1s,
                                              const int* __restrict__ offsets,
                                              const int* __restrict__ ssorted,
                                              const float* __restrict__ dis,
                                              const float* __restrict__ b1,
                                              const float* __restrict__ W2,
                                              float* __restrict__ h2s) {
  const int w = threadIdx.x >> 6;
  const int l = threadIdx.x & 63;
  const int d = blockIdx.x * 4 + w;
  if (d >= NN) return;

  float a0, a1, a2, a3;
  {                                    // self term
    uint2 v = *(const uint2*)(h1s + (size_t)d * HIDN + l * 4);
    a0 = __uint_as_float(v.x << 16);
    a1 = __uint_as_float(v.x & 0xffff0000u);
    a2 = __uint_as_float(v.y << 16);
    a3 = __uint_as_float(v.y & 0xffff0000u);
  }
  const int off0 = offsets[d], off1 = offsets[d + 1];
  int e = off0;
  for (; e + 8 <= off1; e += 8) {      // 8-deep MLP: 8 outstanding row-gathers
    int s0 = ssorted[e],     s1 = ssorted[e + 1], s2 = ssorted[e + 2], s3 = ssorted[e + 3];
    int s4 = ssorted[e + 4], s5 = ssorted[e + 5], s6 = ssorted[e + 6], s7 = ssorted[e + 7];
    uint2 v0 = *(const uint2*)(h1s + (size_t)s0 * HIDN + l * 4);
    uint2 v1 = *(const uint2*)(h1s + (size_t)s1 * HIDN + l * 4);
    uint2 v2 = *(const uint2*)(h1s + (size_t)s2 * HIDN + l * 4);
    uint2 v3 = *(const uint2*)(h1s + (size_t)s3 * HIDN + l * 4);
    uint2 v4 = *(const uint2*)(h1s + (size_t)s4 * HIDN + l * 4);
    uint2 v5 = *(const uint2*)(h1s + (size_t)s5 * HIDN + l * 4);
    uint2 v6 = *(const uint2*)(h1s + (size_t)s6 * HIDN + l * 4);
    uint2 v7 = *(const uint2*)(h1s + (size_t)s7 * HIDN + l * 4);
    ACC_EDGE(v0) ACC_EDGE(v1) ACC_EDGE(v2) ACC_EDGE(v3)
    ACC_EDGE(v4) ACC_EDGE(v5) ACC_EDGE(v6) ACC_EDGE(v7)
  }
  for (; e + 4 <= off1; e += 4) {
    int s0 = ssorted[e], s1 = ssorted[e + 1], s2 = ssorted[e + 2], s3 = ssorted[e + 3];
    uint2 v0 = *(const uint2*)(h1s + (size_t)s0 * HIDN + l * 4);
    uint2 v1 = *(const uint2*)(h1s + (size_t)s1 * HIDN + l * 4);
    uint2 v2 = *(const uint2*)(h1s + (size_t)s2 * HIDN + l * 4);
    uint2 v3 = *(const uint2*)(h1s + (size_t)s3 * HIDN + l * 4);
    ACC_EDGE(v0) ACC_EDGE(v1) ACC_EDGE(v2) ACC_EDGE(v3)
  }
  for (; e < off1; ++e) {
    int s = ssorted[e];
    uint2 v = *(const uint2*)(h1s + (size_t)s * HIDN + l * 4);
    ACC_EDGE(v)
  }

  const float dsd = dis[d];
  const int c0 = l * 4;
  float r0 = fmaxf(a0 * dsd + b1[c0 + 0], 0.f);
  float r1 = fmaxf(a1 * dsd + b1[c0 + 1], 0.f);
  float r2 = fmaxf(a2 * dsd + b1[c0 + 2], 0.f);
  float r3 = fmaxf(a3 * dsd + b1[c0 + 3], 0.f);

  float p0 = r0 * W2[(c0 + 0) * 2] + r1 * W2[(c0 + 1) * 2] +
             r2 * W2[(c0 + 2) * 2] + r3 * W2[(c0 + 3) * 2];
  float p1 = r0 * W2[(c0 + 0) * 2 + 1] + r1 * W2[(c0 + 1) * 2 + 1] +
             r2 * W2[(c0 + 2) * 2 + 1] + r3 * W2[(c0 + 3) * 2 + 1];
#pragma unroll
  for (int o = 1; o < 64; o <<= 1) {
    p0 += __shfl_xor(p0, o);
    p1 += __shfl_xor(p1, o);
  }
  if (l == 0) {
    h2s[(size_t)d * 2 + 0] = dsd * p0;   // pre-scaled by dis[d] for layer-2 gather
    h2s[(size_t)d * 2 + 1] = dsd * p1;
  }
}

// ---------------- layer-2 aggregation (2 cols) ----------------
__global__ void k_agg2(const float* __restrict__ h2s, const int* __restrict__ offsets,
                       const int* __restrict__ ssorted, const float* __restrict__ dis,
                       const float* __restrict__ b2, float* __restrict__ out) {
  int d = blockIdx.x * 256 + threadIdx.x;
  if (d >= NN) return;
  float2 sv = *(const float2*)(h2s + (size_t)d * 2);
  float a0 = sv.x, a1 = sv.y;
  int off0 = offsets[d], off1 = offsets[d + 1];
  int e = off0;
  for (; e + 4 <= off1; e += 4) {
    int s0 = ssorted[e], s1 = ssorted[e + 1], s2 = ssorted[e + 2], s3 = ssorted[e + 3];
    float2 v0 = *(const float2*)(h2s + (size_t)s0 * 2);
    float2 v1 = *(const float2*)(h2s + (size_t)s1 * 2);
    float2 v2 = *(const float2*)(h2s + (size_t)s2 * 2);
    float2 v3 = *(const float2*)(h2s + (size_t)s3 * 2);
    a0 += v0.x + v1.x + v2.x + v3.x;
    a1 += v0.y + v1.y + v2.y + v3.y;
  }
  for (; e < off1; ++e) {
    int s = ssorted[e];
    float2 v = *(const float2*)(h2s + (size_t)s * 2);
    a0 += v.x; a1 += v.y;
  }
  float dsd = dis[d];
  out[(size_t)d * 2 + 0] = dsd * a0 + b2[0];
  out[(size_t)d * 2 + 1] = dsd * a1 + b2[1];
}

extern "C" void kernel_launch(void* const* d_in, const int* in_sizes, int n_in,
                              void* d_out, int out_size, void* d_ws, size_t ws_size,
                              hipStream_t stream) {
  (void)in_sizes; (void)n_in; (void)out_size; (void)ws_size;
  const float* x   = (const float*)d_in[0];
  const float* W1  = (const float*)d_in[1];
  const float* b1  = (const float*)d_in[2];
  const float* W2  = (const float*)d_in[3];
  const float* b2  = (const float*)d_in[4];
  const int*   ei  = (const int*)d_in[5];
  const int* esrc = ei;
  const int* edst = ei + NE;
  float* out = (float*)d_out;

  char* ws = (char*)d_ws;
  // workspace layout (all 16B-aligned), total ~30.3 MB
  unsigned short* h1s = (unsigned short*)(ws + 0);          // 25,600,000 B
  char*  w1t     = ws + 25600000;                           //    262,144 B
  float* dis     = (float*)(ws + 25862144);                 //    200,000 B
  float* h2s     = (float*)(ws + 26062144);                 //    400,000 B
  int*   cnt     = (int*)(ws + 26462144);                   //    200,000 B
  int*   offsets = (int*)(ws + 26662144);                   //    200,004 B
  int*   cursor  = (int*)(ws + 26862208);                   //    200,000 B
  int*   ssorted = (int*)(ws + 27062208);                   //  3,200,000 B
  int*   blocksum= (int*)(ws + 30262208);                   //        196 B
  int*   blockoff= (int*)(ws + 30262464);                   //        196 B

  hipMemsetAsync(cnt, 0, NN * sizeof(int), stream);
  k_hist<<<(NE + 255) / 256, 256, 0, stream>>>(edst, cnt);
  k_blocksum<<<NBLK, 256, 0, stream>>>(cnt, blocksum);
  k_scanblocks<<<1, 64, 0, stream>>>(blocksum, blockoff);
  k_finalize<<<NBLK, 256, 0, stream>>>(cnt, blockoff, offsets, cursor, dis);
  k_scatter<<<(NE + 255) / 256, 256, 0, stream>>>(esrc, edst, cursor, ssorted);
  k_prep_w1t<<<(DIMK * HIDN) / 256, 256, 0, stream>>>(W1, w1t);
  {
    const int nwaves = 2 * ((NN + 31) / 32);        // 3126 one-wave blocks
    k_gemm1<<<nwaves, 64, 0, stream>>>(x, w1t, dis, h1s);
  }
  k_agg1<<<(NN + 3) / 4, 256, 0, stream>>>(h1s, offsets, ssorted, dis, b1, W2, h2s);
  k_agg2<<<(NN + 255) / 256, 256, 0, stream>>>(h2s, offsets, ssorted, dis, b2, out);
}

// Round 11
// 211.450 us; speedup vs baseline: 1.2915x; 1.0052x over previous
//
#include <hip/hip_runtime.h>
#include <stdint.h>

#define NN   50000
#define DIMK 512
#define HIDN 256
#define NE   800000

#define SCAN_ITEMS 4
#define SCAN_BLK 256
#define SCAN_PER_BLOCK (SCAN_ITEMS * SCAN_BLK)              // 1024
#define NBLK ((NN + SCAN_PER_BLOCK - 1) / SCAN_PER_BLOCK)   // 49

typedef float f32x4  __attribute__((ext_vector_type(4)));
typedef float f32x16 __attribute__((ext_vector_type(16)));
typedef short s16x8  __attribute__((ext_vector_type(8)));

static __device__ __forceinline__ unsigned short f2bf(float f) {
  union { float f; uint32_t u; } v; v.f = f;
  uint32_t u = v.u;
  u += 0x7fffu + ((u >> 16) & 1u);   // RNE
  return (unsigned short)(u >> 16);
}

static __device__ __forceinline__ uint32_t cvt_pk_bf16(float lo, float hi) {
  uint32_t r;
  asm("v_cvt_pk_bf16_f32 %0, %1, %2" : "=v"(r) : "v"(lo), "v"(hi));
  return r;   // low16 = bf16(lo), high16 = bf16(hi), RNE
}

// ---------------- degree histogram ----------------
__global__ void k_hist(const int* __restrict__ edst, int* __restrict__ cnt) {
  int e = blockIdx.x * 256 + threadIdx.x;
  if (e < NE) atomicAdd(&cnt[edst[e]], 1);
}

// ---------------- device-wide scan, stage 1: per-block sums ----------------
__global__ __launch_bounds__(256) void k_blocksum(const int* __restrict__ cnt,
                                                  int* __restrict__ blocksum) {
  const int t = threadIdx.x;
  const int base = blockIdx.x * SCAN_PER_BLOCK + t * SCAN_ITEMS;
  int s = 0;
#pragma unroll
  for (int j = 0; j < SCAN_ITEMS; ++j) { int i = base + j; if (i < NN) s += cnt[i]; }
#pragma unroll
  for (int o = 1; o < 64; o <<= 1) s += __shfl_xor(s, o);
  __shared__ int wsum[4];
  if ((t & 63) == 0) wsum[t >> 6] = s;
  __syncthreads();
  if (t == 0) blocksum[blockIdx.x] = wsum[0] + wsum[1] + wsum[2] + wsum[3];
}

// ---------------- stage 2: scan the 49 block sums (one wave) ----------------
__global__ void k_scanblocks(const int* __restrict__ blocksum, int* __restrict__ blockoff) {
  const int t = threadIdx.x;   // 64 threads
  int own = (t < NBLK) ? blocksum[t] : 0;
  int v = own;
#pragma unroll
  for (int o = 1; o < 64; o <<= 1) { int u = __shfl_up(v, o); if (t >= o) v += u; }
  if (t < NBLK) blockoff[t] = v - own;   // exclusive
}

// ---------------- stage 3: local scan + write offsets/cursor/dis ----------------
__global__ __launch_bounds__(256) void k_finalize(const int* __restrict__ cnt,
                                                  const int* __restrict__ blockoff,
                                                  int* __restrict__ offsets,
                                                  int* __restrict__ cursor,
                                                  float* __restrict__ dis) {
  const int t = threadIdx.x;
  const int l = t & 63, w = t >> 6;
  const int base = blockIdx.x * SCAN_PER_BLOCK + t * SCAN_ITEMS;
  int c[SCAN_ITEMS]; int s = 0;
#pragma unroll
  for (int j = 0; j < SCAN_ITEMS; ++j) { int i = base + j; c[j] = (i < NN) ? cnt[i] : 0; s += c[j]; }
  const int own = s;
#pragma unroll
  for (int o = 1; o < 64; o <<= 1) { int u = __shfl_up(s, o); if (l >= o) s += u; }
  __shared__ int wt[4];
  if (l == 63) wt[w] = s;
  __syncthreads();
  int waveoff = 0;
  for (int ww = 0; ww < w; ++ww) waveoff += wt[ww];
  int run = blockoff[blockIdx.x] + waveoff + (s - own);   // exclusive prefix
#pragma unroll
  for (int j = 0; j < SCAN_ITEMS; ++j) {
    int i = base + j;
    if (i < NN) {
      offsets[i] = run;
      cursor[i]  = run;
      dis[i] = rsqrtf((float)(c[j] + 1));   // +1 self loop
      run += c[j];
    }
  }
  if (blockIdx.x == 0 && t == 0) offsets[NN] = NE;
}

// ---------------- CSR scatter ----------------
__global__ void k_scatter(const int* __restrict__ esrc, const int* __restrict__ edst,
                          int* __restrict__ cursor, int* __restrict__ ssorted) {
  int e = blockIdx.x * 256 + threadIdx.x;
  if (e < NE) {
    int d = edst[e];
    int p = atomicAdd(&cursor[d], 1);
    ssorted[p] = esrc[e];
  }
}

// ---------------- W1^T -> bf16, fragment-contiguous image for 32x32x16 MFMA ----
// fragment (t, j): 1KB, lane l, elem i at byte (t*8+j)*1024 + l*16 + 2*i
// holds element k = t*16 + 8*(l>>5) + i, col = j*32 + (l&31)
__global__ void k_prep_w1t(const float* __restrict__ W1, char* __restrict__ w1t) {
  int tid = blockIdx.x * 256 + threadIdx.x;   // 512*256 = 131072 = DIMK*HIDN
  int c  = tid & 255;
  int k  = tid >> 8;
  int t  = k >> 4;
  int kk = k & 15;
  int g  = kk >> 3;
  int i  = kk & 7;
  int j  = c >> 5;
  int cc = c & 31;
  unsigned short v = f2bf(W1[k * HIDN + c]);
  *(unsigned short*)(w1t + (t * 8 + j) * 1024 + (g * 32 + cc) * 16 + i * 2) = v;
}

// ---------------- GEMM1 (R4 datapath, DEEP register pipeline) ---------------
// One independent wave per (32-row stripe, 128-col half). No LDS, no barriers.
// A rotation 8 deep (covers L3 ~600cy), B rotation 4 deep (covers L2 ~300cy).
// All rotation indices are compile-time constants (T&7 / T&3 in a fully
// unrolled 32-step loop) — R4's proven idiom, deeper. ~215 regs -> 2 waves/EU.
__global__ __launch_bounds__(64, 2) void k_gemm1(const float* __restrict__ x,
                                                 const char* __restrict__ w1t,
                                                 const float* __restrict__ dis,
                                                 unsigned short* __restrict__ h1s) {
  const int l = threadIdx.x;           // 0..63, one wave per block
  const int wid = blockIdx.x;
  const int stripe = wid >> 1;
  const int R0 = stripe * 32;
  if (R0 >= NN) return;
  const int j0 = (wid & 1) * 4;       // column half: fragments j0..j0+3
  const int h = l >> 5;
  int ra = R0 + (l & 31);
  if (ra >= NN) ra = NN - 1;

  const float4* ap = (const float4*)(x + (size_t)ra * DIMK) + h * 2;
  const char* wb = w1t + j0 * 1024 + l * 16;

  f32x16 acc[4];
#pragma unroll
  for (int j = 0; j < 4; ++j)
#pragma unroll
    for (int g = 0; g < 16; ++g) acc[j][g] = 0.f;

  // prologue: A steps 0..7, B steps 0..3
  float4 Aa[8], Ab[8];
#pragma unroll
  for (int t = 0; t < 8; ++t) { Aa[t] = ap[t * 4]; Ab[t] = ap[t * 4 + 1]; }
  s16x8 Bv[4][4];
#pragma unroll
  for (int t = 0; t < 4; ++t)
#pragma unroll
    for (int j = 0; j < 4; ++j)
      Bv[t][j] = *(const s16x8*)(wb + t * 8192 + j * 1024);

#pragma unroll
  for (int T = 0; T < 32; ++T) {
    union { s16x8 v; uint32_t u[4]; } AF;
    AF.u[0] = cvt_pk_bf16(Aa[T & 7].x, Aa[T & 7].y);
    AF.u[1] = cvt_pk_bf16(Aa[T & 7].z, Aa[T & 7].w);
    AF.u[2] = cvt_pk_bf16(Ab[T & 7].x, Ab[T & 7].y);
    AF.u[3] = cvt_pk_bf16(Ab[T & 7].z, Ab[T & 7].w);
#pragma unroll
    for (int j = 0; j < 4; ++j)
      acc[j] = __builtin_amdgcn_mfma_f32_32x32x16_bf16(AF.v, Bv[T & 3][j], acc[j], 0, 0, 0);
    if (T + 8 < 32) {                  // refill A slot (same slot: (T+8)&7 == T&7)
      Aa[T & 7] = ap[(T + 8) * 4];
      Ab[T & 7] = ap[(T + 8) * 4 + 1];
    }
    if (T + 4 < 32) {                  // refill B slot ((T+4)&3 == T&3)
#pragma unroll
      for (int j = 0; j < 4; ++j)
        Bv[T & 3][j] = *(const s16x8*)(wb + (T + 4) * 8192 + j * 1024);
    }
  }

  // epilogue: D col = (j0+j)*32 + (l&31), row = (g&3) + 8*(g>>2) + 4*(l>>5)
  const int cc = l & 31;
  float dv[16];
#pragma unroll
  for (int g = 0; g < 16; ++g) {
    int row = R0 + (g & 3) + 8 * (g >> 2) + 4 * h;
    dv[g] = (row < NN) ? dis[row] : 0.f;
  }
#pragma unroll
  for (int j = 0; j < 4; ++j) {
#pragma unroll
    for (int g = 0; g < 16; ++g) {
      int row = R0 + (g & 3) + 8 * (g >> 2) + 4 * h;
      if (row < NN)
        h1s[(size_t)row * HIDN + (j0 + j) * 32 + cc] = f2bf(acc[j][g] * dv[g]);
    }
  }
}

// ---------------- fused: aggregate h1s (CSR) + b1 + ReLU + @W2 -> h2s (pre-scaled) ----------------
#define ACC_EDGE(VV)                                                            \
  a0 += __uint_as_float((VV).x << 16);                                          \
  a1 += __uint_as_float((VV).x & 0xffff0000u);                                  \
  a2 += __uint_as_float((VV).y << 16);                                          \
  a3 += __uint_as_float((VV).y & 0xffff0000u);

__global__ __launch_bounds__(256) void k_agg1(const unsigned short* __restrict__ h1s,
                                              const int* __restrict__ offsets,
                                              const int* __restrict__ ssorted,
                                              const float* __restrict__ dis,
                                              const float* __restrict__ b1,
                                              const float* __restrict__ W2,
                                              float* __restrict__ h2s) {
  const int w = threadIdx.x >> 6;
  const int l = threadIdx.x & 63;
  const int d = blockIdx.x * 4 + w;
  if (d >= NN) return;

  float a0, a1, a2, a3;
  {                                    // self term
    uint2 v = *(const uint2*)(h1s + (size_t)d * HIDN + l * 4);
    a0 = __uint_as_float(v.x << 16);
    a1 = __uint_as_float(v.x & 0xffff0000u);
    a2 = __uint_as_float(v.y << 16);
    a3 = __uint_as_float(v.y & 0xffff0000u);
  }
  const int off0 = offsets[d], off1 = offsets[d + 1];
  int e = off0;
  for (; e + 8 <= off1; e += 8) {      // 8-deep MLP: 8 outstanding row-gathers
    int s0 = ssorted[e],     s1 = ssorted[e + 1], s2 = ssorted[e + 2], s3 = ssorted[e + 3];
    int s4 = ssorted[e + 4], s5 = ssorted[e + 5], s6 = ssorted[e + 6], s7 = ssorted[e + 7];
    uint2 v0 = *(const uint2*)(h1s + (size_t)s0 * HIDN + l * 4);
    uint2 v1 = *(const uint2*)(h1s + (size_t)s1 * HIDN + l * 4);
    uint2 v2 = *(const uint2*)(h1s + (size_t)s2 * HIDN + l * 4);
    uint2 v3 = *(const uint2*)(h1s + (size_t)s3 * HIDN + l * 4);
    uint2 v4 = *(const uint2*)(h1s + (size_t)s4 * HIDN + l * 4);
    uint2 v5 = *(const uint2*)(h1s + (size_t)s5 * HIDN + l * 4);
    uint2 v6 = *(const uint2*)(h1s + (size_t)s6 * HIDN + l * 4);
    uint2 v7 = *(const uint2*)(h1s + (size_t)s7 * HIDN + l * 4);
    ACC_EDGE(v0) ACC_EDGE(v1) ACC_EDGE(v2) ACC_EDGE(v3)
    ACC_EDGE(v4) ACC_EDGE(v5) ACC_EDGE(v6) ACC_EDGE(v7)
  }
  for (; e + 4 <= off1; e += 4) {
    int s0 = ssorted[e], s1 = ssorted[e + 1], s2 = ssorted[e + 2], s3 = ssorted[e + 3];
    uint2 v0 = *(const uint2*)(h1s + (size_t)s0 * HIDN + l * 4);
    uint2 v1 = *(const uint2*)(h1s + (size_t)s1 * HIDN + l * 4);
    uint2 v2 = *(const uint2*)(h1s + (size_t)s2 * HIDN + l * 4);
    uint2 v3 = *(const uint2*)(h1s + (size_t)s3 * HIDN + l * 4);
    ACC_EDGE(v0) ACC_EDGE(v1) ACC_EDGE(v2) ACC_EDGE(v3)
  }
  for (; e < off1; ++e) {
    int s = ssorted[e];
    uint2 v = *(const uint2*)(h1s + (size_t)s * HIDN + l * 4);
    ACC_EDGE(v)
  }

  const float dsd = dis[d];
  const int c0 = l * 4;
  float r0 = fmaxf(a0 * dsd + b1[c0 + 0], 0.f);
  float r1 = fmaxf(a1 * dsd + b1[c0 + 1], 0.f);
  float r2 = fmaxf(a2 * dsd + b1[c0 + 2], 0.f);
  float r3 = fmaxf(a3 * dsd + b1[c0 + 3], 0.f);

  float p0 = r0 * W2[(c0 + 0) * 2] + r1 * W2[(c0 + 1) * 2] +
             r2 * W2[(c0 + 2) * 2] + r3 * W2[(c0 + 3) * 2];
  float p1 = r0 * W2[(c0 + 0) * 2 + 1] + r1 * W2[(c0 + 1) * 2 + 1] +
             r2 * W2[(c0 + 2) * 2 + 1] + r3 * W2[(c0 + 3) * 2 + 1];
#pragma unroll
  for (int o = 1; o < 64; o <<= 1) {
    p0 += __shfl_xor(p0, o);
    p1 += __shfl_xor(p1, o);
  }
  if (l == 0) {
    h2s[(size_t)d * 2 + 0] = dsd * p0;   // pre-scaled by dis[d] for layer-2 gather
    h2s[(size_t)d * 2 + 1] = dsd * p1;
  }
}

// ---------------- layer-2 aggregation (2 cols) ----------------
__global__ void k_agg2(const float* __restrict__ h2s, const int* __restrict__ offsets,
                       const int* __restrict__ ssorted, const float* __restrict__ dis,
                       const float* __restrict__ b2, float* __restrict__ out) {
  int d = blockIdx.x * 256 + threadIdx.x;
  if (d >= NN) return;
  float2 sv = *(const float2*)(h2s + (size_t)d * 2);
  float a0 = sv.x, a1 = sv.y;
  int off0 = offsets[d], off1 = offsets[d + 1];
  int e = off0;
  for (; e + 4 <= off1; e += 4) {
    int s0 = ssorted[e], s1 = ssorted[e + 1], s2 = ssorted[e + 2], s3 = ssorted[e + 3];
    float2 v0 = *(const float2*)(h2s + (size_t)s0 * 2);
    float2 v1 = *(const float2*)(h2s + (size_t)s1 * 2);
    float2 v2 = *(const float2*)(h2s + (size_t)s2 * 2);
    float2 v3 = *(const float2*)(h2s + (size_t)s3 * 2);
    a0 += v0.x + v1.x + v2.x + v3.x;
    a1 += v0.y + v1.y + v2.y + v3.y;
  }
  for (; e < off1; ++e) {
    int s = ssorted[e];
    float2 v = *(const float2*)(h2s + (size_t)s * 2);
    a0 += v.x; a1 += v.y;
  }
  float dsd = dis[d];
  out[(size_t)d * 2 + 0] = dsd * a0 + b2[0];
  out[(size_t)d * 2 + 1] = dsd * a1 + b2[1];
}

extern "C" void kernel_launch(void* const* d_in, const int* in_sizes, int n_in,
                              void* d_out, int out_size, void* d_ws, size_t ws_size,
                              hipStream_t stream) {
  (void)in_sizes; (void)n_in; (void)out_size; (void)ws_size;
  const float* x   = (const float*)d_in[0];
  const float* W1  = (const float*)d_in[1];
  const float* b1  = (const float*)d_in[2];
  const float* W2  = (const float*)d_in[3];
  const float* b2  = (const float*)d_in[4];
  const int*   ei  = (const int*)d_in[5];
  const int* esrc = ei;
  const int* edst = ei + NE;
  float* out = (float*)d_out;

  char* ws = (char*)d_ws;
  // workspace layout (all 16B-aligned), total ~30.3 MB
  unsigned short* h1s = (unsigned short*)(ws + 0);          // 25,600,000 B
  char*  w1t     = ws + 25600000;                           //    262,144 B
  float* dis     = (float*)(ws + 25862144);                 //    200,000 B
  float* h2s     = (float*)(ws + 26062144);                 //    400,000 B
  int*   cnt     = (int*)(ws + 26462144);                   //    200,000 B
  int*   offsets = (int*)(ws + 26662144);                   //    200,004 B
  int*   cursor  = (int*)(ws + 26862208);                   //    200,000 B
  int*   ssorted = (int*)(ws + 27062208);                   //  3,200,000 B
  int*   blocksum= (int*)(ws + 30262208);                   //        196 B
  int*   blockoff= (int*)(ws + 30262464);                   //        196 B

  hipMemsetAsync(cnt, 0, NN * sizeof(int), stream);
  k_hist<<<(NE + 255) / 256, 256, 0, stream>>>(edst, cnt);
  k_blocksum<<<NBLK, 256, 0, stream>>>(cnt, blocksum);
  k_scanblocks<<<1, 64, 0, stream>>>(blocksum, blockoff);
  k_finalize<<<NBLK, 256, 0, stream>>>(cnt, blockoff, offsets, cursor, dis);
  k_scatter<<<(NE + 255) / 256, 256, 0, stream>>>(esrc, edst, cursor, ssorted);
  k_prep_w1t<<<(DIMK * HIDN) / 256, 256, 0, stream>>>(W1, w1t);
  {
    const int nwaves = 2 * ((NN + 31) / 32);        // 3126 one-wave blocks
    k_gemm1<<<nwaves, 64, 0, stream>>>(x, w1t, dis, h1s);
  }
  k_agg1<<<(NN + 3) / 4, 256, 0, stream>>>(h1s, offsets, ssorted, dis, b1, W2, h2s);
  k_agg2<<<(NN + 255) / 256, 256, 0, stream>>>(h2s, offsets, ssorted, dis, b2, out);
}